// Round 17
// baseline (211.273 us; speedup 1.0000x reference)
//
#include <hip/hip_runtime.h>
#include <hip/hip_bf16.h>
#include <math.h>

#define NN 100000
#define NE 1000000
#define DD 64
#define NG 128
#define NL 3

#define NBUK 196
#define EPB 2048
#define NBLK ((NE + EPB - 1) / EPB)
#define BCAP 6144
#define NDC 64
#define POOL_ROWS 128
#define DPERM_BLOCKS ((NN + 1023) / 1024)

typedef unsigned short ushort_t;
typedef unsigned int u32;
typedef __attribute__((ext_vector_type(8))) short short8v;
typedef __attribute__((ext_vector_type(2))) float f32x2;
typedef __attribute__((ext_vector_type(4))) float f32x4;
typedef __attribute__((ext_vector_type(4))) unsigned int u32x4;

__device__ __forceinline__ ushort_t f2bf(float f) {
    __hip_bfloat16 h = __float2bfloat16(f);
    return *reinterpret_cast<ushort_t*>(&h);
}
__device__ __forceinline__ unsigned cvtpk(float lo, float hi) {
    unsigned r;
    asm("v_cvt_pk_bf16_f32 %0, %1, %2" : "=v"(r) : "v"(lo), "v"(hi));
    return r;
}
__device__ __forceinline__ f32x2 bfpair(u32 u) {
    f32x2 r;
    r.x = __builtin_bit_cast(float, u << 16);
    r.y = __builtin_bit_cast(float, u & 0xffff0000u);
    return r;
}
template <bool HI>
__device__ __forceinline__ f32x2 f8pair(u32 u) {
    return __builtin_amdgcn_cvt_pk_f32_fp8(u, HI);
}
__device__ __forceinline__ float sum8(float x) {
    int v = __builtin_bit_cast(int, x);
    x += __builtin_bit_cast(float, __builtin_amdgcn_update_dpp(0, v, 0xB1, 0xF, 0xF, true));
    v = __builtin_bit_cast(int, x);
    x += __builtin_bit_cast(float, __builtin_amdgcn_update_dpp(0, v, 0x4E, 0xF, 0xF, true));
    v = __builtin_bit_cast(int, x);
    x += __builtin_bit_cast(float, __builtin_amdgcn_update_dpp(0, v, 0x141, 0xF, 0xF, true));
    return x;
}

// ---------------- zero: gcur + gdh + gdcur ----------------

__global__ __launch_bounds__(256) void zero_k(int* __restrict__ gcur, int* __restrict__ gdh,
                                              int* __restrict__ gdcur) {
    if (blockIdx.x == 0 && threadIdx.x < NBUK) gcur[threadIdx.x] = 0;
    if (blockIdx.x == 1 && threadIdx.x < NDC) { gdh[threadIdx.x] = 0; gdcur[threadIdx.x] = 0; }
}

// ---------------- fused: packw + bin + out-zero ----------------

__global__ __launch_bounds__(256) void fused_k(const float* __restrict__ Wq, const float* __restrict__ Wk,
                                               const float* __restrict__ Wv, const float* __restrict__ Ws_,
                                               ushort_t* __restrict__ wpack,
                                               const int* __restrict__ src, const int* __restrict__ dst,
                                               u32* __restrict__ binbuf, int* __restrict__ gcur,
                                               float* __restrict__ out, int totOut) {
    __shared__ int hist[NBUK];
    __shared__ int excl[NBUK];
    __shared__ int cur[NBUK];
    __shared__ int gbase[NBUK];
    __shared__ int tmp[256];
    __shared__ u32 pairs[EPB];
    __shared__ unsigned char bukid[EPB];

    int b = blockIdx.x, t = threadIdx.x;
    if (b < NL * 4) {
        if (t < 64) {
            int mat = b & 3, layer = b >> 2;
            const float* W = ((mat == 0) ? Wq : (mat == 1) ? Wk : (mat == 2) ? Wv : Ws_) + layer * DD * DD;
#pragma unroll
            for (int ct = 0; ct < 4; ct++)
#pragma unroll
                for (int ks = 0; ks < 2; ks++)
#pragma unroll
                    for (int j = 0; j < 8; j++) {
                        float v = W[(ks * 32 + (t >> 4) * 8 + j) * DD + ct * 16 + (t & 15)];
                        wpack[((size_t)(b * 8 + ct * 2 + ks)) * 512 + t * 8 + j] = f2bf(v);
                    }
        }
        return;
    }
    b -= NL * 4;
    if (b >= NBLK) {
        int i = (b - NBLK) * 256 + t;
        if (i < totOut) out[i] = 0.f;
        return;
    }
    int e0 = b * EPB;
    int totvalid = NE - e0; if (totvalid > EPB) totvalid = EPB;

    for (int i = t; i < NBUK; i += 256) hist[i] = 0;
    __syncthreads();

    int mysrc[8], mydst[8];
#pragma unroll
    for (int i = 0; i < 8; i++) {
        int e = e0 + i * 256 + t;
        bool v = e < NE;
        mysrc[i] = v ? src[e] : -1;
        mydst[i] = v ? dst[e] : -1;
        if (v) atomicAdd(&hist[mydst[i] >> 9], 1);
    }
    __syncthreads();

    int v = (t < NBUK) ? hist[t] : 0;
    tmp[t] = v;
    __syncthreads();
#pragma unroll
    for (int off = 1; off < 256; off <<= 1) {
        int a = (t >= off) ? tmp[t - off] : 0;
        __syncthreads();
        tmp[t] += a;
        __syncthreads();
    }
    if (t < NBUK) { excl[t] = tmp[t] - v; cur[t] = tmp[t] - v; }
    __syncthreads();

#pragma unroll
    for (int i = 0; i < 8; i++) {
        if (mydst[i] >= 0) {
            int bb = mydst[i] >> 9;
            int p = atomicAdd(&cur[bb], 1);
            pairs[p] = ((u32)(mydst[i] & 511) << 17) | (u32)mysrc[i];
            bukid[p] = (unsigned char)bb;
        }
    }
    if (t < NBUK && v > 0) gbase[t] = atomicAdd(&gcur[t], v);
    __syncthreads();

    for (int i = t; i < totvalid; i += 256) {
        int bb = bukid[i];
        int idx = gbase[bb] + (i - excl[bb]);
        if (idx < BCAP) binbuf[(size_t)bb * BCAP + idx] = pairs[i];
    }
}

// ---------------- csr_k: CSR finalize + degree-class histogram ----------------

__global__ __launch_bounds__(256) void csr_k(const u32* __restrict__ binbuf,
                                             const int* __restrict__ gcur,
                                             int* __restrict__ rowstart,
                                             int* __restrict__ csr_src,
                                             int* __restrict__ gdh) {
    __shared__ u32 pairs[BCAP];
    __shared__ int csrb[BCAP];
    __shared__ int deg[512];
    __shared__ int excl[512];
    __shared__ int cur[512];
    __shared__ int tmp[512];
    __shared__ int bt[256];
    __shared__ int ch[NDC];
    int b = blockIdx.x;
    int t = threadIdx.x;

    int bv = 0;
    if (t < NBUK) { bv = gcur[t]; if (bv > BCAP) bv = BCAP; }
    bt[t] = bv;
    __syncthreads();
#pragma unroll
    for (int off = 1; off < 256; off <<= 1) {
        int a = (t >= off) ? bt[t - off] : 0;
        __syncthreads();
        bt[t] += a;
        __syncthreads();
    }
    int base = (b == 0) ? 0 : bt[b - 1];
    int T = bt[b] - base;
    if (b == 0 && t == 0) rowstart[NN] = bt[NBUK - 1];
    int nbase = b << 9;

    for (int i = t; i < 512; i += 256) deg[i] = 0;
    if (t < NDC) ch[t] = 0;
    for (int i = t; i < T; i += 256) pairs[i] = binbuf[(size_t)b * BCAP + i];
    __syncthreads();
    for (int i = t; i < T; i += 256) atomicAdd(&deg[pairs[i] >> 17], 1);
    __syncthreads();

    for (int i = t; i < 512; i += 256) {
        if (nbase + i < NN) {
            int d = deg[i]; if (d > NDC - 1) d = NDC - 1;
            atomicAdd(&ch[d], 1);
        }
    }

    int v0 = deg[t], v1 = deg[t + 256];
    tmp[t] = v0; tmp[t + 256] = v1;
    __syncthreads();
#pragma unroll
    for (int off = 1; off < 512; off <<= 1) {
        int a0 = (t >= off) ? tmp[t - off] : 0;
        int i1 = t + 256;
        int a1 = (i1 >= off) ? tmp[i1 - off] : 0;
        __syncthreads();
        tmp[t] += a0; tmp[i1] += a1;
        __syncthreads();
    }
    excl[t] = tmp[t] - v0; excl[t + 256] = tmp[t + 256] - v1;
    cur[t] = excl[t]; cur[t + 256] = excl[t + 256];
    if (t < NDC && ch[t]) atomicAdd(&gdh[t], ch[t]);
    __syncthreads();

    for (int i = t; i < 512; i += 256) {
        int n = nbase + i;
        if (n < NN) rowstart[n] = base + excl[i];
    }

    for (int i = t; i < T; i += 256) {
        u32 p = pairs[i];
        int pos = atomicAdd(&cur[p >> 17], 1);
        csrb[pos] = (int)(p & 0x1FFFFu);
    }
    __syncthreads();
    for (int i = t; i < T; i += 256) csr_src[base + i] = csrb[i];
}

// ---------------- dperm body: self-sufficient (local rescan of gdh) ----------------

__device__ __forceinline__ void dperm_body(const int* __restrict__ rowstart,
                                           const int* __restrict__ gdh,
                                           int* __restrict__ gdcur,
                                           int* __restrict__ perm, int pb) {
    __shared__ int h[NDC];
    __shared__ int cur[NDC];
    __shared__ int cbase[NDC];
    int t = threadIdx.x;
    if (t < NDC) {
        h[t] = 0;
        int v = gdh[t];
        int inc = v;
#pragma unroll
        for (int off = 1; off < NDC; off <<= 1) {
            int u = __shfl_up(inc, off);
            if (t >= off) inc += u;
        }
        cbase[t] = inc - v;
    }
    __syncthreads();
    int n0 = pb * 1024;
    int myd[4];
#pragma unroll
    for (int i = 0; i < 4; i++) {
        int n = n0 + i * 256 + t;
        myd[i] = -1;
        if (n < NN) {
            int d = rowstart[n + 1] - rowstart[n];
            if (d > NDC - 1) d = NDC - 1;
            myd[i] = d;
            atomicAdd(&h[d], 1);
        }
    }
    __syncthreads();
    if (t < NDC) cur[t] = h[t] ? (cbase[t] + atomicAdd(&gdcur[t], h[t])) : 0;
    __syncthreads();
#pragma unroll
    for (int i = 0; i < 4; i++) {
        if (myd[i] >= 0) {
            int pos = atomicAdd(&cur[myd[i]], 1);
            perm[pos] = n0 + i * 256 + t;
        }
    }
}

// ---------------- pool body ----------------

__device__ __forceinline__ void pool_body(const ushort_t* __restrict__ h,
                                          const int* __restrict__ batch,
                                          float* __restrict__ pooled, int pb) {
    int i0 = pb * POOL_ROWS;
    int i1 = i0 + POOL_ROWS; if (i1 > NN) i1 = NN;
    int lane = threadIdx.x & 63;
    int wv = threadIdx.x >> 6;
    float acc = 0.f;
    int gc = -1;
    for (int i = i0 + wv; i < i1; i += 4) {
        int gi = batch[i];
        if (gi != gc) {
            if (gc >= 0) atomicAdd(&pooled[gc * DD + lane], acc);
            gc = gi; acc = 0.f;
        }
        unsigned u = ((unsigned)h[(size_t)i * DD + lane]) << 16;
        acc += __builtin_bit_cast(float, u);
    }
    if (gc >= 0) atomicAdd(&pooled[gc * DD + lane], acc);
}

// ---------------- fused 4-matrix MFMA GEMM (+ tail: pool OR dperm) ----------------

__global__ __launch_bounds__(256) void gemm4pool_k(const ushort_t* __restrict__ hbf,
                                                   const float* __restrict__ xf32,
                                                   const ushort_t* __restrict__ wpl,
                                                   const float* __restrict__ bq_, const float* __restrict__ bk_,
                                                   const float* __restrict__ bv_, const float* __restrict__ bs_,
                                                   ushort_t* __restrict__ qo, unsigned char* __restrict__ kv8,
                                                   ushort_t* __restrict__ so,
                                                   const int* __restrict__ batch,
                                                   float* __restrict__ pooledPrev, int gtiles, int tailMode,
                                                   const int* __restrict__ rowstart,
                                                   const int* __restrict__ gdh,
                                                   int* __restrict__ gdcur,
                                                   int* __restrict__ perm) {
    __shared__ char stage[4][2304];
    int blk = blockIdx.x;
    if (blk >= gtiles) {
        if (tailMode == 1) pool_body(hbf, batch, pooledPrev, blk - gtiles);
        else dperm_body(rowstart, gdh, gdcur, perm, blk - gtiles);
        return;
    }
    int t = threadIdx.x;
    int lane = t & 63, wv = t >> 6;
    int ln = lane & 15, lq = lane >> 4;
    int rowbase = blk * 64;
    char* st = stage[wv];
    bool isbf = (wv == 0) || (wv == 3);
    int kvoff = (wv == 1) ? 0 : 64;

    const float* bsel = (wv == 0) ? bq_ : (wv == 1) ? bk_ : (wv == 2) ? bv_ : bs_;
    ushort_t* osel    = (wv == 0) ? qo : so;

    short8v wfrag[4][2];
#pragma unroll
    for (int ct = 0; ct < 4; ct++)
#pragma unroll
        for (int ks = 0; ks < 2; ks++)
            wfrag[ct][ks] = *(const short8v*)&wpl[((size_t)(wv * 8 + ct * 2 + ks)) * 512 + lane * 8];

    float4 bias[4];
#pragma unroll
    for (int ct = 0; ct < 4; ct++) bias[ct] = *(const float4*)&bsel[ct * 16 + lq * 4];

#pragma unroll
    for (int rt = 0; rt < 4; rt++) {
        int grow0 = rowbase + rt * 16 + ln;
        int gr = grow0 < NN ? grow0 : NN - 1;
        short8v h0, h1;
        if (xf32) {
            float4 f0 = *(const float4*)&xf32[(size_t)gr * DD + lq * 8];
            float4 f1 = *(const float4*)&xf32[(size_t)gr * DD + lq * 8 + 4];
            float4 f2 = *(const float4*)&xf32[(size_t)gr * DD + 32 + lq * 8];
            float4 f3 = *(const float4*)&xf32[(size_t)gr * DD + 32 + lq * 8 + 4];
            u32x4 p0, p1;
            p0[0] = cvtpk(f0.x, f0.y); p0[1] = cvtpk(f0.z, f0.w);
            p0[2] = cvtpk(f1.x, f1.y); p0[3] = cvtpk(f1.z, f1.w);
            p1[0] = cvtpk(f2.x, f2.y); p1[1] = cvtpk(f2.z, f2.w);
            p1[2] = cvtpk(f3.x, f3.y); p1[3] = cvtpk(f3.z, f3.w);
            h0 = __builtin_bit_cast(short8v, p0);
            h1 = __builtin_bit_cast(short8v, p1);
        } else {
            h0 = *(const short8v*)&hbf[(size_t)gr * DD + lq * 8];
            h1 = *(const short8v*)&hbf[(size_t)gr * DD + 32 + lq * 8];
        }
#pragma unroll
        for (int ct = 0; ct < 4; ct++) {
            f32x4 acc;
            acc[0] = bias[ct].x; acc[1] = bias[ct].y; acc[2] = bias[ct].z; acc[3] = bias[ct].w;
            acc = __builtin_amdgcn_mfma_f32_16x16x32_bf16(wfrag[ct][0], h0, acc, 0, 0, 0);
            acc = __builtin_amdgcn_mfma_f32_16x16x32_bf16(wfrag[ct][1], h1, acc, 0, 0, 0);
            if (isbf) {
                uint2 pk;
                pk.x = cvtpk(acc[0], acc[1]);
                pk.y = cvtpk(acc[2], acc[3]);
                *(uint2*)(st + ln * 144 + ct * 32 + lq * 8) = pk;
            } else {
                int pk8 = __builtin_amdgcn_cvt_pk_fp8_f32(acc[0], acc[1], 0, false);
                pk8 = __builtin_amdgcn_cvt_pk_fp8_f32(acc[2], acc[3], pk8, true);
                *(u32*)(st + ln * 80 + ct * 16 + lq * 4) = (u32)pk8;
            }
        }
        if (isbf) {
#pragma unroll
            for (int hh = 0; hh < 2; hh++) {
                int r = (lane >> 3) + 8 * hh;
                int c = lane & 7;
                u32x4 d = *(const u32x4*)(st + r * 144 + c * 16);
                int grow = rowbase + rt * 16 + r;
                if (grow < NN) *(u32x4*)&osel[(size_t)grow * DD + c * 8] = d;
            }
        } else {
            int r = lane >> 2;
            int c = lane & 3;
            u32x4 d = *(const u32x4*)(st + r * 80 + c * 16);
            int grow = rowbase + rt * 16 + r;
            if (grow < NN) *(u32x4*)(kv8 + (size_t)grow * 128 + kvoff + c * 16) = d;
        }
    }
}

// ---------------- aggregate: 8 nodes/wave, quad-edge pipeline ----------------
// Per iteration: process quad A (4 edges), issue kv for quad C (indices arrived
// 2 iters ago), issue csr for quad E (2 quads ahead of kv). Clamps target the
// node's own last edge (cache-hot).

#define SCLOG2E 0.18033688011112042f  // 0.125 * log2(e)

#define LOADQ(K0, V0, K1, V1, K2, V2, K3, V3, S0, S1, S2, S3)            \
    K0 = *(const uint2*)(kv8 + (size_t)(S0) * 128 + 8 * j);              \
    V0 = *(const uint2*)(kv8 + (size_t)(S0) * 128 + 64 + 8 * j);         \
    K1 = *(const uint2*)(kv8 + (size_t)(S1) * 128 + 8 * j);              \
    V1 = *(const uint2*)(kv8 + (size_t)(S1) * 128 + 64 + 8 * j);         \
    K2 = *(const uint2*)(kv8 + (size_t)(S2) * 128 + 8 * j);              \
    V2 = *(const uint2*)(kv8 + (size_t)(S2) * 128 + 64 + 8 * j);         \
    K3 = *(const uint2*)(kv8 + (size_t)(S3) * 128 + 8 * j);              \
    V3 = *(const uint2*)(kv8 + (size_t)(S3) * 128 + 64 + 8 * j);

__global__ __launch_bounds__(256) void agg_k(const ushort_t* __restrict__ qb,
                                             const unsigned char* __restrict__ kv8,
                                             const ushort_t* __restrict__ skb,
                                             const int* __restrict__ rowstart,
                                             const int* __restrict__ csr_src,
                                             const int* __restrict__ perm,
                                             ushort_t* __restrict__ hout) {
    int wv = threadIdx.x >> 6, lane = threadIdx.x & 63;
    int g = lane >> 3, j = lane & 7;
    int slot = blockIdx.x * 32 + wv * 8 + g;
    if (slot >= NN) return;
    int nid = perm[(NN - 1) - slot];     // longest-first
    int r0 = rowstart[nid];
    int r1 = rowstart[nid + 1];

    u32x4 qa = *(const u32x4*)(qb + ((u32)nid << 6) + ((u32)j << 3));
    f32x2 q0 = bfpair(qa.x), q1 = bfpair(qa.y), q2 = bfpair(qa.z), q3 = bfpair(qa.w);

    float m = -1.0e38f, se = 0.f;
    f32x2 a0 = {0.f, 0.f}, a1 = {0.f, 0.f}, a2 = {0.f, 0.f}, a3 = {0.f, 0.f};

    int clampE = r1 - 1; if (clampE < 0) clampE = 0;
    int e = r0;
    // csr indices: quads A,B (for prologue kv), C,D in queue
    int sA0 = csr_src[e      < clampE ? e      : clampE];
    int sA1 = csr_src[e + 1  < clampE ? e + 1  : clampE];
    int sA2 = csr_src[e + 2  < clampE ? e + 2  : clampE];
    int sA3 = csr_src[e + 3  < clampE ? e + 3  : clampE];
    int sB0 = csr_src[e + 4  < clampE ? e + 4  : clampE];
    int sB1 = csr_src[e + 5  < clampE ? e + 5  : clampE];
    int sB2 = csr_src[e + 6  < clampE ? e + 6  : clampE];
    int sB3 = csr_src[e + 7  < clampE ? e + 7  : clampE];
    int sC0 = csr_src[e + 8  < clampE ? e + 8  : clampE];
    int sC1 = csr_src[e + 9  < clampE ? e + 9  : clampE];
    int sC2 = csr_src[e + 10 < clampE ? e + 10 : clampE];
    int sC3 = csr_src[e + 11 < clampE ? e + 11 : clampE];
    int sD0 = csr_src[e + 12 < clampE ? e + 12 : clampE];
    int sD1 = csr_src[e + 13 < clampE ? e + 13 : clampE];
    int sD2 = csr_src[e + 14 < clampE ? e + 14 : clampE];
    int sD3 = csr_src[e + 15 < clampE ? e + 15 : clampE];

    uint2 kA0, vA0, kA1, vA1, kA2, vA2, kA3, vA3;
    uint2 kB0, vB0, kB1, vB1, kB2, vB2, kB3, vB3;
    LOADQ(kA0, vA0, kA1, vA1, kA2, vA2, kA3, vA3, sA0, sA1, sA2, sA3);
    LOADQ(kB0, vB0, kB1, vB1, kB2, vB2, kB3, vB3, sB0, sB1, sB2, sB3);

    while (__ballot(e < r1)) {
        // csr for quad E (e+16)
        int e16 = e + 16;
        int sE0 = csr_src[e16     < clampE ? e16     : clampE];
        int sE1 = csr_src[e16 + 1 < clampE ? e16 + 1 : clampE];
        int sE2 = csr_src[e16 + 2 < clampE ? e16 + 2 : clampE];
        int sE3 = csr_src[e16 + 3 < clampE ? e16 + 3 : clampE];
        // kv for quad C (indices arrived 2 iterations ago)
        uint2 kC0, vC0, kC1, vC1, kC2, vC2, kC3, vC3;
        LOADQ(kC0, vC0, kC1, vC1, kC2, vC2, kC3, vC3, sC0, sC1, sC2, sC3);

        // process quad A: 4 independent dot chains
        f32x2 d0 = q0 * f8pair<false>(kA0.x);
        d0 += q1 * f8pair<true >(kA0.x);
        d0 += q2 * f8pair<false>(kA0.y);
        d0 += q3 * f8pair<true >(kA0.y);
        f32x2 d1 = q0 * f8pair<false>(kA1.x);
        d1 += q1 * f8pair<true >(kA1.x);
        d1 += q2 * f8pair<false>(kA1.y);
        d1 += q3 * f8pair<true >(kA1.y);
        f32x2 d2 = q0 * f8pair<false>(kA2.x);
        d2 += q1 * f8pair<true >(kA2.x);
        d2 += q2 * f8pair<false>(kA2.y);
        d2 += q3 * f8pair<true >(kA2.y);
        f32x2 d3 = q0 * f8pair<false>(kA3.x);
        d3 += q1 * f8pair<true >(kA3.x);
        d3 += q2 * f8pair<false>(kA3.y);
        d3 += q3 * f8pair<true >(kA3.y);
        float dp0 = sum8(d0.x + d0.y);
        float dp1 = sum8(d1.x + d1.y);
        float dp2 = sum8(d2.x + d2.y);
        float dp3 = sum8(d3.x + d3.y);

        bool act0 = e < r1, act1 = e + 1 < r1, act2 = e + 2 < r1, act3 = e + 3 < r1;
        float sc0 = dp0 * SCLOG2E, sc1 = dp1 * SCLOG2E;
        float sc2 = dp2 * SCLOG2E, sc3 = dp3 * SCLOG2E;
        float pm = fmaxf(fmaxf(act0 ? sc0 : -1.0e38f, act1 ? sc1 : -1.0e38f),
                         fmaxf(act2 ? sc2 : -1.0e38f, act3 ? sc3 : -1.0e38f));
        float w0 = 0.f, w1 = 0.f, w2 = 0.f, w3 = 0.f;
        if (pm > -1.0e37f) {
            if (pm > m + 11.5f) {
                float cc = exp2f(m - pm);
                se *= cc; a0 *= cc; a1 *= cc; a2 *= cc; a3 *= cc;
                m = pm;
            }
            if (act0) w0 = exp2f(sc0 - m);
            if (act1) w1 = exp2f(sc1 - m);
            if (act2) w2 = exp2f(sc2 - m);
            if (act3) w3 = exp2f(sc3 - m);
        }
        se += (w0 + w1) + (w2 + w3);
        a0 += f8pair<false>(vA0.x) * w0 + f8pair<false>(vA1.x) * w1
            + f8pair<false>(vA2.x) * w2 + f8pair<false>(vA3.x) * w3;
        a1 += f8pair<true >(vA0.x) * w0 + f8pair<true >(vA1.x) * w1
            + f8pair<true >(vA2.x) * w2 + f8pair<true >(vA3.x) * w3;
        a2 += f8pair<false>(vA0.y) * w0 + f8pair<false>(vA1.y) * w1
            + f8pair<false>(vA2.y) * w2 + f8pair<false>(vA3.y) * w3;
        a3 += f8pair<true >(vA0.y) * w0 + f8pair<true >(vA1.y) * w1
            + f8pair<true >(vA2.y) * w2 + f8pair<true >(vA3.y) * w3;

        e += 4;
        sC0 = sD0; sC1 = sD1; sC2 = sD2; sC3 = sD3;
        sD0 = sE0; sD1 = sE1; sD2 = sE2; sD3 = sE3;
        kA0 = kB0; vA0 = vB0; kA1 = kB1; vA1 = vB1;
        kA2 = kB2; vA2 = vB2; kA3 = kB3; vA3 = vB3;
        kB0 = kC0; vB0 = vC0; kB1 = kC1; vB1 = vC1;
        kB2 = kC2; vB2 = vC2; kB3 = kC3; vB3 = vC3;
    }

    float inv = 1.0f / (se + 1e-16f);
    u32x4 sk = *(const u32x4*)(skb + ((u32)nid << 6) + ((u32)j << 3));
    f32x2 o0 = a0 * inv + bfpair(sk.x);
    f32x2 o1 = a1 * inv + bfpair(sk.y);
    f32x2 o2 = a2 * inv + bfpair(sk.z);
    f32x2 o3 = a3 * inv + bfpair(sk.w);
    u32x4 pk;
    pk.x = cvtpk(fmaxf(o0.x, 0.f), fmaxf(o0.y, 0.f));
    pk.y = cvtpk(fmaxf(o1.x, 0.f), fmaxf(o1.y, 0.f));
    pk.z = cvtpk(fmaxf(o2.x, 0.f), fmaxf(o2.y, 0.f));
    pk.w = cvtpk(fmaxf(o3.x, 0.f), fmaxf(o3.y, 0.f));
    *(u32x4*)(hout + ((u32)nid << 6) + ((u32)j << 3)) = pk;
}

// ---------------- standalone pool (last layer) ----------------

__global__ __launch_bounds__(256) void pool_k(const ushort_t* __restrict__ h,
                                              const int* __restrict__ batch,
                                              float* __restrict__ pooled) {
    pool_body(h, batch, pooled, blockIdx.x);
}

// ---------------- head ----------------

__global__ __launch_bounds__(64) void head_k(const float* __restrict__ pooled2,
                                             const float* __restrict__ W1,
                                             const float* __restrict__ b1,
                                             const float* __restrict__ W2,
                                             const float* __restrict__ b2,
                                             float* __restrict__ out) {
    int g = blockIdx.x;
    int c = threadIdx.x;
    __shared__ float pg[64], p[64];
    pg[c] = pooled2[g * DD + c];
    __syncthreads();
    float a = b1[c];
#pragma unroll 8
    for (int kk = 0; kk < 64; kk++) a += pg[kk] * W1[kk * DD + c];
    p[c] = fmaxf(a, 0.f);
    __syncthreads();
    if (c < 10) {
        float o = b2[c];
#pragma unroll 8
        for (int kk = 0; kk < 64; kk++) o += p[kk] * W2[kk * 10 + c];
        out[g * 10 + c] = o;
    }
}

// ---------------- launch ----------------

extern "C" void kernel_launch(void* const* d_in, const int* in_sizes, int n_in,
                              void* d_out, int out_size, void* d_ws, size_t ws_size,
                              hipStream_t stream) {
    const float* x    = (const float*)d_in[0];
    const int*   ei   = (const int*)d_in[1];
    const int*   batch= (const int*)d_in[2];
    const float* Wq   = (const float*)d_in[3];
    const float* bq   = (const float*)d_in[4];
    const float* Wk   = (const float*)d_in[5];
    const float* bk   = (const float*)d_in[6];
    const float* Wv   = (const float*)d_in[7];
    const float* bv   = (const float*)d_in[8];
    const float* Wsp  = (const float*)d_in[9];
    const float* bsp  = (const float*)d_in[10];
    const float* W1   = (const float*)d_in[11];
    const float* b1   = (const float*)d_in[12];
    const float* W2   = (const float*)d_in[13];
    const float* b2   = (const float*)d_in[14];
    float* out = (float*)d_out;
    float* pooled = out + NG * 10;

    const int* srcv = ei;
    const int* dstv = ei + NE;

    const size_t NEL = (size_t)NN * DD;
    ushort_t* hbf = (ushort_t*)d_ws;
    ushort_t* qb  = hbf + NEL;
    ushort_t* skb = qb  + NEL;
    unsigned char* kv8 = (unsigned char*)(skb + NEL);
    u32* binbuf   = (u32*)(kv8 + (size_t)NN * 128);
    int* gcur     = (int*)(binbuf + (size_t)NBUK * BCAP);
    int* gdh      = gcur + NBUK;
    int* gdcur    = gdh + NDC;
    int* rowstart = gdcur + NDC;
    int* csr_src  = rowstart + (NN + 1);
    int* perm     = csr_src + NE;
    ushort_t* wpack = (ushort_t*)(perm + NN);

    int totOut = NG * 10 + NL * NG * DD;
    int zeroBlocks = (totOut + 255) / 256;

    zero_k<<<2, 256, 0, stream>>>(gcur, gdh, gdcur);
    fused_k<<<NL * 4 + NBLK + zeroBlocks, 256, 0, stream>>>(
        Wq, Wk, Wv, Wsp, wpack, srcv, dstv, binbuf, gcur, out, totOut);
    csr_k<<<NBUK, 256, 0, stream>>>(binbuf, gcur, rowstart, csr_src, gdh);

    int gtiles = (NN + 63) / 64;
    int poolblocks = (NN + POOL_ROWS - 1) / POOL_ROWS;
    for (int l = 0; l < NL; l++) {
        int tailMode = (l == 0) ? 2 : 1;
        int extra = (l == 0) ? DPERM_BLOCKS : poolblocks;
        gemm4pool_k<<<gtiles + extra, 256, 0, stream>>>(
            hbf, (l == 0) ? x : nullptr, wpack + (size_t)l * 4 * 8 * 512,
            bq + l * DD, bk + l * DD, bv + l * DD, bsp + l * DD,
            qb, kv8, skb, batch,
            (l > 0) ? (pooled + (l - 1) * NG * DD) : nullptr, gtiles, tailMode,
            rowstart, gdh, gdcur, perm);
        agg_k<<<(NN + 31) / 32, 256, 0, stream>>>(qb, kv8, skb, rowstart, csr_src, perm, hbf);
    }
    pool_k<<<poolblocks, 256, 0, stream>>>(hbf, batch, pooled + 2 * NG * DD);
    head_k<<<NG, 64, 0, stream>>>(pooled + 2 * NG * DD, W1, b1, W2, b2, out);
}

// Round 18
// 205.795 us; speedup vs baseline: 1.0266x; 1.0266x over previous
//
#include <hip/hip_runtime.h>
#include <hip/hip_bf16.h>
#include <math.h>

#define NN 100000
#define NE 1000000
#define DD 64
#define NG 128
#define NL 3

#define NBUK 196
#define EPB 2048
#define NBLK ((NE + EPB - 1) / EPB)
#define BCAP 6144
#define NDC 64
#define POOL_ROWS 128
#define DPERM_BLOCKS ((NN + 1023) / 1024)

typedef unsigned short ushort_t;
typedef unsigned int u32;
typedef __attribute__((ext_vector_type(8))) short short8v;
typedef __attribute__((ext_vector_type(2))) float f32x2;
typedef __attribute__((ext_vector_type(4))) float f32x4;
typedef __attribute__((ext_vector_type(4))) unsigned int u32x4;

__device__ __forceinline__ ushort_t f2bf(float f) {
    __hip_bfloat16 h = __float2bfloat16(f);
    return *reinterpret_cast<ushort_t*>(&h);
}
__device__ __forceinline__ unsigned cvtpk(float lo, float hi) {
    unsigned r;
    asm("v_cvt_pk_bf16_f32 %0, %1, %2" : "=v"(r) : "v"(lo), "v"(hi));
    return r;
}
__device__ __forceinline__ f32x2 bfpair(u32 u) {
    f32x2 r;
    r.x = __builtin_bit_cast(float, u << 16);
    r.y = __builtin_bit_cast(float, u & 0xffff0000u);
    return r;
}
template <bool HI>
__device__ __forceinline__ f32x2 f8pair(u32 u) {
    return __builtin_amdgcn_cvt_pk_f32_fp8(u, HI);
}
__device__ __forceinline__ float sum8(float x) {
    int v = __builtin_bit_cast(int, x);
    x += __builtin_bit_cast(float, __builtin_amdgcn_update_dpp(0, v, 0xB1, 0xF, 0xF, true));
    v = __builtin_bit_cast(int, x);
    x += __builtin_bit_cast(float, __builtin_amdgcn_update_dpp(0, v, 0x4E, 0xF, 0xF, true));
    v = __builtin_bit_cast(int, x);
    x += __builtin_bit_cast(float, __builtin_amdgcn_update_dpp(0, v, 0x141, 0xF, 0xF, true));
    return x;
}

// ---------------- zero: gcur + gdh + gdcur ----------------

__global__ __launch_bounds__(256) void zero_k(int* __restrict__ gcur, int* __restrict__ gdh,
                                              int* __restrict__ gdcur) {
    if (blockIdx.x == 0 && threadIdx.x < NBUK) gcur[threadIdx.x] = 0;
    if (blockIdx.x == 1 && threadIdx.x < NDC) { gdh[threadIdx.x] = 0; gdcur[threadIdx.x] = 0; }
}

// ---------------- fused: packw + bin + out-zero ----------------

__global__ __launch_bounds__(256) void fused_k(const float* __restrict__ Wq, const float* __restrict__ Wk,
                                               const float* __restrict__ Wv, const float* __restrict__ Ws_,
                                               ushort_t* __restrict__ wpack,
                                               const int* __restrict__ src, const int* __restrict__ dst,
                                               u32* __restrict__ binbuf, int* __restrict__ gcur,
                                               float* __restrict__ out, int totOut) {
    __shared__ int hist[NBUK];
    __shared__ int excl[NBUK];
    __shared__ int cur[NBUK];
    __shared__ int gbase[NBUK];
    __shared__ int tmp[256];
    __shared__ u32 pairs[EPB];
    __shared__ unsigned char bukid[EPB];

    int b = blockIdx.x, t = threadIdx.x;
    if (b < NL * 4) {
        if (t < 64) {
            int mat = b & 3, layer = b >> 2;
            const float* W = ((mat == 0) ? Wq : (mat == 1) ? Wk : (mat == 2) ? Wv : Ws_) + layer * DD * DD;
#pragma unroll
            for (int ct = 0; ct < 4; ct++)
#pragma unroll
                for (int ks = 0; ks < 2; ks++)
#pragma unroll
                    for (int j = 0; j < 8; j++) {
                        float v = W[(ks * 32 + (t >> 4) * 8 + j) * DD + ct * 16 + (t & 15)];
                        wpack[((size_t)(b * 8 + ct * 2 + ks)) * 512 + t * 8 + j] = f2bf(v);
                    }
        }
        return;
    }
    b -= NL * 4;
    if (b >= NBLK) {
        int i = (b - NBLK) * 256 + t;
        if (i < totOut) out[i] = 0.f;
        return;
    }
    int e0 = b * EPB;
    int totvalid = NE - e0; if (totvalid > EPB) totvalid = EPB;

    for (int i = t; i < NBUK; i += 256) hist[i] = 0;
    __syncthreads();

    int mysrc[8], mydst[8];
#pragma unroll
    for (int i = 0; i < 8; i++) {
        int e = e0 + i * 256 + t;
        bool v = e < NE;
        mysrc[i] = v ? src[e] : -1;
        mydst[i] = v ? dst[e] : -1;
        if (v) atomicAdd(&hist[mydst[i] >> 9], 1);
    }
    __syncthreads();

    int v = (t < NBUK) ? hist[t] : 0;
    tmp[t] = v;
    __syncthreads();
#pragma unroll
    for (int off = 1; off < 256; off <<= 1) {
        int a = (t >= off) ? tmp[t - off] : 0;
        __syncthreads();
        tmp[t] += a;
        __syncthreads();
    }
    if (t < NBUK) { excl[t] = tmp[t] - v; cur[t] = tmp[t] - v; }
    __syncthreads();

#pragma unroll
    for (int i = 0; i < 8; i++) {
        if (mydst[i] >= 0) {
            int bb = mydst[i] >> 9;
            int p = atomicAdd(&cur[bb], 1);
            pairs[p] = ((u32)(mydst[i] & 511) << 17) | (u32)mysrc[i];
            bukid[p] = (unsigned char)bb;
        }
    }
    if (t < NBUK && v > 0) gbase[t] = atomicAdd(&gcur[t], v);
    __syncthreads();

    for (int i = t; i < totvalid; i += 256) {
        int bb = bukid[i];
        int idx = gbase[bb] + (i - excl[bb]);
        if (idx < BCAP) binbuf[(size_t)bb * BCAP + idx] = pairs[i];
    }
}

// ---------------- csr_k: CSR finalize + degree-class histogram ----------------

__global__ __launch_bounds__(256) void csr_k(const u32* __restrict__ binbuf,
                                             const int* __restrict__ gcur,
                                             int* __restrict__ rowstart,
                                             int* __restrict__ csr_src,
                                             int* __restrict__ gdh) {
    __shared__ u32 pairs[BCAP];
    __shared__ int csrb[BCAP];
    __shared__ int deg[512];
    __shared__ int excl[512];
    __shared__ int cur[512];
    __shared__ int tmp[512];
    __shared__ int bt[256];
    __shared__ int ch[NDC];
    int b = blockIdx.x;
    int t = threadIdx.x;

    int bv = 0;
    if (t < NBUK) { bv = gcur[t]; if (bv > BCAP) bv = BCAP; }
    bt[t] = bv;
    __syncthreads();
#pragma unroll
    for (int off = 1; off < 256; off <<= 1) {
        int a = (t >= off) ? bt[t - off] : 0;
        __syncthreads();
        bt[t] += a;
        __syncthreads();
    }
    int base = (b == 0) ? 0 : bt[b - 1];
    int T = bt[b] - base;
    if (b == 0 && t == 0) rowstart[NN] = bt[NBUK - 1];
    int nbase = b << 9;

    for (int i = t; i < 512; i += 256) deg[i] = 0;
    if (t < NDC) ch[t] = 0;
    for (int i = t; i < T; i += 256) pairs[i] = binbuf[(size_t)b * BCAP + i];
    __syncthreads();
    for (int i = t; i < T; i += 256) atomicAdd(&deg[pairs[i] >> 17], 1);
    __syncthreads();

    for (int i = t; i < 512; i += 256) {
        if (nbase + i < NN) {
            int d = deg[i]; if (d > NDC - 1) d = NDC - 1;
            atomicAdd(&ch[d], 1);
        }
    }

    int v0 = deg[t], v1 = deg[t + 256];
    tmp[t] = v0; tmp[t + 256] = v1;
    __syncthreads();
#pragma unroll
    for (int off = 1; off < 512; off <<= 1) {
        int a0 = (t >= off) ? tmp[t - off] : 0;
        int i1 = t + 256;
        int a1 = (i1 >= off) ? tmp[i1 - off] : 0;
        __syncthreads();
        tmp[t] += a0; tmp[i1] += a1;
        __syncthreads();
    }
    excl[t] = tmp[t] - v0; excl[t + 256] = tmp[t + 256] - v1;
    cur[t] = excl[t]; cur[t + 256] = excl[t + 256];
    if (t < NDC && ch[t]) atomicAdd(&gdh[t], ch[t]);
    __syncthreads();

    for (int i = t; i < 512; i += 256) {
        int n = nbase + i;
        if (n < NN) rowstart[n] = base + excl[i];
    }

    for (int i = t; i < T; i += 256) {
        u32 p = pairs[i];
        int pos = atomicAdd(&cur[p >> 17], 1);
        csrb[pos] = (int)(p & 0x1FFFFu);
    }
    __syncthreads();
    for (int i = t; i < T; i += 256) csr_src[base + i] = csrb[i];
}

// ---------------- dperm body: self-sufficient (local rescan of gdh) ----------------

__device__ __forceinline__ void dperm_body(const int* __restrict__ rowstart,
                                           const int* __restrict__ gdh,
                                           int* __restrict__ gdcur,
                                           int* __restrict__ perm, int pb) {
    __shared__ int h[NDC];
    __shared__ int cur[NDC];
    __shared__ int cbase[NDC];
    int t = threadIdx.x;
    if (t < NDC) {
        h[t] = 0;
        int v = gdh[t];
        int inc = v;
#pragma unroll
        for (int off = 1; off < NDC; off <<= 1) {
            int u = __shfl_up(inc, off);
            if (t >= off) inc += u;
        }
        cbase[t] = inc - v;
    }
    __syncthreads();
    int n0 = pb * 1024;
    int myd[4];
#pragma unroll
    for (int i = 0; i < 4; i++) {
        int n = n0 + i * 256 + t;
        myd[i] = -1;
        if (n < NN) {
            int d = rowstart[n + 1] - rowstart[n];
            if (d > NDC - 1) d = NDC - 1;
            myd[i] = d;
            atomicAdd(&h[d], 1);
        }
    }
    __syncthreads();
    if (t < NDC) cur[t] = h[t] ? (cbase[t] + atomicAdd(&gdcur[t], h[t])) : 0;
    __syncthreads();
#pragma unroll
    for (int i = 0; i < 4; i++) {
        if (myd[i] >= 0) {
            int pos = atomicAdd(&cur[myd[i]], 1);
            perm[pos] = n0 + i * 256 + t;
        }
    }
}

// ---------------- pool body ----------------

__device__ __forceinline__ void pool_body(const ushort_t* __restrict__ h,
                                          const int* __restrict__ batch,
                                          float* __restrict__ pooled, int pb) {
    int i0 = pb * POOL_ROWS;
    int i1 = i0 + POOL_ROWS; if (i1 > NN) i1 = NN;
    int lane = threadIdx.x & 63;
    int wv = threadIdx.x >> 6;
    float acc = 0.f;
    int gc = -1;
    for (int i = i0 + wv; i < i1; i += 4) {
        int gi = batch[i];
        if (gi != gc) {
            if (gc >= 0) atomicAdd(&pooled[gc * DD + lane], acc);
            gc = gi; acc = 0.f;
        }
        unsigned u = ((unsigned)h[(size_t)i * DD + lane]) << 16;
        acc += __builtin_bit_cast(float, u);
    }
    if (gc >= 0) atomicAdd(&pooled[gc * DD + lane], acc);
}

// ---------------- fused 4-matrix MFMA GEMM (+ tail: pool OR dperm) ----------------

__global__ __launch_bounds__(256) void gemm4pool_k(const ushort_t* __restrict__ hbf,
                                                   const float* __restrict__ xf32,
                                                   const ushort_t* __restrict__ wpl,
                                                   const float* __restrict__ bq_, const float* __restrict__ bk_,
                                                   const float* __restrict__ bv_, const float* __restrict__ bs_,
                                                   ushort_t* __restrict__ qo, unsigned char* __restrict__ kv8,
                                                   ushort_t* __restrict__ so,
                                                   const int* __restrict__ batch,
                                                   float* __restrict__ pooledPrev, int gtiles, int tailMode,
                                                   const int* __restrict__ rowstart,
                                                   const int* __restrict__ gdh,
                                                   int* __restrict__ gdcur,
                                                   int* __restrict__ perm) {
    __shared__ char stage[4][2304];
    int blk = blockIdx.x;
    if (blk >= gtiles) {
        if (tailMode == 1) pool_body(hbf, batch, pooledPrev, blk - gtiles);
        else dperm_body(rowstart, gdh, gdcur, perm, blk - gtiles);
        return;
    }
    int t = threadIdx.x;
    int lane = t & 63, wv = t >> 6;
    int ln = lane & 15, lq = lane >> 4;
    int rowbase = blk * 64;
    char* st = stage[wv];
    bool isbf = (wv == 0) || (wv == 3);
    int kvoff = (wv == 1) ? 0 : 64;

    const float* bsel = (wv == 0) ? bq_ : (wv == 1) ? bk_ : (wv == 2) ? bv_ : bs_;
    ushort_t* osel    = (wv == 0) ? qo : so;

    short8v wfrag[4][2];
#pragma unroll
    for (int ct = 0; ct < 4; ct++)
#pragma unroll
        for (int ks = 0; ks < 2; ks++)
            wfrag[ct][ks] = *(const short8v*)&wpl[((size_t)(wv * 8 + ct * 2 + ks)) * 512 + lane * 8];

    float4 bias[4];
#pragma unroll
    for (int ct = 0; ct < 4; ct++) bias[ct] = *(const float4*)&bsel[ct * 16 + lq * 4];

#pragma unroll
    for (int rt = 0; rt < 4; rt++) {
        int grow0 = rowbase + rt * 16 + ln;
        int gr = grow0 < NN ? grow0 : NN - 1;
        short8v h0, h1;
        if (xf32) {
            float4 f0 = *(const float4*)&xf32[(size_t)gr * DD + lq * 8];
            float4 f1 = *(const float4*)&xf32[(size_t)gr * DD + lq * 8 + 4];
            float4 f2 = *(const float4*)&xf32[(size_t)gr * DD + 32 + lq * 8];
            float4 f3 = *(const float4*)&xf32[(size_t)gr * DD + 32 + lq * 8 + 4];
            u32x4 p0, p1;
            p0[0] = cvtpk(f0.x, f0.y); p0[1] = cvtpk(f0.z, f0.w);
            p0[2] = cvtpk(f1.x, f1.y); p0[3] = cvtpk(f1.z, f1.w);
            p1[0] = cvtpk(f2.x, f2.y); p1[1] = cvtpk(f2.z, f2.w);
            p1[2] = cvtpk(f3.x, f3.y); p1[3] = cvtpk(f3.z, f3.w);
            h0 = __builtin_bit_cast(short8v, p0);
            h1 = __builtin_bit_cast(short8v, p1);
        } else {
            h0 = *(const short8v*)&hbf[(size_t)gr * DD + lq * 8];
            h1 = *(const short8v*)&hbf[(size_t)gr * DD + 32 + lq * 8];
        }
#pragma unroll
        for (int ct = 0; ct < 4; ct++) {
            f32x4 acc;
            acc[0] = bias[ct].x; acc[1] = bias[ct].y; acc[2] = bias[ct].z; acc[3] = bias[ct].w;
            acc = __builtin_amdgcn_mfma_f32_16x16x32_bf16(wfrag[ct][0], h0, acc, 0, 0, 0);
            acc = __builtin_amdgcn_mfma_f32_16x16x32_bf16(wfrag[ct][1], h1, acc, 0, 0, 0);
            if (isbf) {
                uint2 pk;
                pk.x = cvtpk(acc[0], acc[1]);
                pk.y = cvtpk(acc[2], acc[3]);
                *(uint2*)(st + ln * 144 + ct * 32 + lq * 8) = pk;
            } else {
                int pk8 = __builtin_amdgcn_cvt_pk_fp8_f32(acc[0], acc[1], 0, false);
                pk8 = __builtin_amdgcn_cvt_pk_fp8_f32(acc[2], acc[3], pk8, true);
                *(u32*)(st + ln * 80 + ct * 16 + lq * 4) = (u32)pk8;
            }
        }
        if (isbf) {
#pragma unroll
            for (int hh = 0; hh < 2; hh++) {
                int r = (lane >> 3) + 8 * hh;
                int c = lane & 7;
                u32x4 d = *(const u32x4*)(st + r * 144 + c * 16);
                int grow = rowbase + rt * 16 + r;
                if (grow < NN) *(u32x4*)&osel[(size_t)grow * DD + c * 8] = d;
            }
        } else {
            int r = lane >> 2;
            int c = lane & 3;
            u32x4 d = *(const u32x4*)(st + r * 80 + c * 16);
            int grow = rowbase + rt * 16 + r;
            if (grow < NN) *(u32x4*)(kv8 + (size_t)grow * 128 + kvoff + c * 16) = d;
        }
    }
}

// ---------------- aggregate: 8 nodes/wave, 1 group/node, pair pipeline ----------------

#define SCLOG2E 0.18033688011112042f  // 0.125 * log2(e)

__global__ __launch_bounds__(256) void agg_k(const ushort_t* __restrict__ qb,
                                             const unsigned char* __restrict__ kv8,
                                             const ushort_t* __restrict__ skb,
                                             const int* __restrict__ rowstart,
                                             const int* __restrict__ csr_src,
                                             const int* __restrict__ perm,
                                             ushort_t* __restrict__ hout) {
    int wv = threadIdx.x >> 6, lane = threadIdx.x & 63;
    int g = lane >> 3, j = lane & 7;
    int slot = blockIdx.x * 32 + wv * 8 + g;
    if (slot >= NN) return;
    int nid = perm[(NN - 1) - slot];     // longest-first
    int r0 = rowstart[nid];
    int r1 = rowstart[nid + 1];

    u32x4 qa = *(const u32x4*)(qb + ((u32)nid << 6) + ((u32)j << 3));
    f32x2 q0 = bfpair(qa.x), q1 = bfpair(qa.y), q2 = bfpair(qa.z), q3 = bfpair(qa.w);

    float m = -1.0e38f, se = 0.f;
    f32x2 a0 = {0.f, 0.f}, a1 = {0.f, 0.f}, a2 = {0.f, 0.f}, a3 = {0.f, 0.f};

    int clampE = r1 - 1; if (clampE < 0) clampE = 0;
    int e = r0;
    int sA0 = csr_src[e     < clampE ? e     : clampE];
    int sA1 = csr_src[e + 1 < clampE ? e + 1 : clampE];
    int sB0 = csr_src[e + 2 < clampE ? e + 2 : clampE];
    int sB1 = csr_src[e + 3 < clampE ? e + 3 : clampE];
    int sC0 = csr_src[e + 4 < clampE ? e + 4 : clampE];
    int sC1 = csr_src[e + 5 < clampE ? e + 5 : clampE];
    int sD0 = csr_src[e + 6 < clampE ? e + 6 : clampE];
    int sD1 = csr_src[e + 7 < clampE ? e + 7 : clampE];
    uint2 kA0 = *(const uint2*)(kv8 + (size_t)sA0 * 128 + 8 * j);
    uint2 vA0 = *(const uint2*)(kv8 + (size_t)sA0 * 128 + 64 + 8 * j);
    uint2 kA1 = *(const uint2*)(kv8 + (size_t)sA1 * 128 + 8 * j);
    uint2 vA1 = *(const uint2*)(kv8 + (size_t)sA1 * 128 + 64 + 8 * j);
    uint2 kB0 = *(const uint2*)(kv8 + (size_t)sB0 * 128 + 8 * j);
    uint2 vB0 = *(const uint2*)(kv8 + (size_t)sB0 * 128 + 64 + 8 * j);
    uint2 kB1 = *(const uint2*)(kv8 + (size_t)sB1 * 128 + 8 * j);
    uint2 vB1 = *(const uint2*)(kv8 + (size_t)sB1 * 128 + 64 + 8 * j);

    while (__ballot(e < r1)) {
        int e8 = e + 8;
        int sE0 = csr_src[e8     < clampE ? e8     : clampE];
        int sE1 = csr_src[e8 + 1 < clampE ? e8 + 1 : clampE];
        uint2 kC0 = *(const uint2*)(kv8 + (size_t)sC0 * 128 + 8 * j);
        uint2 vC0 = *(const uint2*)(kv8 + (size_t)sC0 * 128 + 64 + 8 * j);
        uint2 kC1 = *(const uint2*)(kv8 + (size_t)sC1 * 128 + 8 * j);
        uint2 vC1 = *(const uint2*)(kv8 + (size_t)sC1 * 128 + 64 + 8 * j);

        f32x2 d0 = q0 * f8pair<false>(kA0.x);
        d0 += q1 * f8pair<true >(kA0.x);
        d0 += q2 * f8pair<false>(kA0.y);
        d0 += q3 * f8pair<true >(kA0.y);
        f32x2 d1 = q0 * f8pair<false>(kA1.x);
        d1 += q1 * f8pair<true >(kA1.x);
        d1 += q2 * f8pair<false>(kA1.y);
        d1 += q3 * f8pair<true >(kA1.y);
        float dp0 = sum8(d0.x + d0.y);
        float dp1 = sum8(d1.x + d1.y);

        bool act0 = e < r1, act1 = e + 1 < r1;
        float sc0 = dp0 * SCLOG2E, sc1 = dp1 * SCLOG2E;
        float s0a = act0 ? sc0 : -1.0e38f;
        float s1a = act1 ? sc1 : -1.0e38f;
        float pm = fmaxf(s0a, s1a);
        float w0 = 0.f, w1 = 0.f;
        if (pm > -1.0e37f) {
            if (pm <= m + 11.5f) {
                if (act0) w0 = exp2f(sc0 - m);
                if (act1) w1 = exp2f(sc1 - m);
            } else {
                float cc = exp2f(m - pm);
                se *= cc; a0 *= cc; a1 *= cc; a2 *= cc; a3 *= cc;
                m = pm;
                if (act0) w0 = exp2f(sc0 - pm);
                if (act1) w1 = exp2f(sc1 - pm);
            }
        }
        se += w0 + w1;
        a0 += f8pair<false>(vA0.x) * w0 + f8pair<false>(vA1.x) * w1;
        a1 += f8pair<true >(vA0.x) * w0 + f8pair<true >(vA1.x) * w1;
        a2 += f8pair<false>(vA0.y) * w0 + f8pair<false>(vA1.y) * w1;
        a3 += f8pair<true >(vA0.y) * w0 + f8pair<true >(vA1.y) * w1;

        e += 2;
        sC0 = sD0; sC1 = sD1; sD0 = sE0; sD1 = sE1;
        kA0 = kB0; vA0 = vB0; kA1 = kB1; vA1 = vB1;
        kB0 = kC0; vB0 = vC0; kB1 = kC1; vB1 = vC1;
    }

    // no cross-group combine: group == node
    float inv = 1.0f / (se + 1e-16f);
    u32x4 sk = *(const u32x4*)(skb + ((u32)nid << 6) + ((u32)j << 3));
    f32x2 o0 = a0 * inv + bfpair(sk.x);
    f32x2 o1 = a1 * inv + bfpair(sk.y);
    f32x2 o2 = a2 * inv + bfpair(sk.z);
    f32x2 o3 = a3 * inv + bfpair(sk.w);
    u32x4 pk;
    pk.x = cvtpk(fmaxf(o0.x, 0.f), fmaxf(o0.y, 0.f));
    pk.y = cvtpk(fmaxf(o1.x, 0.f), fmaxf(o1.y, 0.f));
    pk.z = cvtpk(fmaxf(o2.x, 0.f), fmaxf(o2.y, 0.f));
    pk.w = cvtpk(fmaxf(o3.x, 0.f), fmaxf(o3.y, 0.f));
    *(u32x4*)(hout + ((u32)nid << 6) + ((u32)j << 3)) = pk;
}

// ---------------- standalone pool (last layer) ----------------

__global__ __launch_bounds__(256) void pool_k(const ushort_t* __restrict__ h,
                                              const int* __restrict__ batch,
                                              float* __restrict__ pooled) {
    pool_body(h, batch, pooled, blockIdx.x);
}

// ---------------- head ----------------

__global__ __launch_bounds__(64) void head_k(const float* __restrict__ pooled2,
                                             const float* __restrict__ W1,
                                             const float* __restrict__ b1,
                                             const float* __restrict__ W2,
                                             const float* __restrict__ b2,
                                             float* __restrict__ out) {
    int g = blockIdx.x;
    int c = threadIdx.x;
    __shared__ float pg[64], p[64];
    pg[c] = pooled2[g * DD + c];
    __syncthreads();
    float a = b1[c];
#pragma unroll 8
    for (int kk = 0; kk < 64; kk++) a += pg[kk] * W1[kk * DD + c];
    p[c] = fmaxf(a, 0.f);
    __syncthreads();
    if (c < 10) {
        float o = b2[c];
#pragma unroll 8
        for (int kk = 0; kk < 64; kk++) o += p[kk] * W2[kk * 10 + c];
        out[g * 10 + c] = o;
    }
}

// ---------------- launch ----------------

extern "C" void kernel_launch(void* const* d_in, const int* in_sizes, int n_in,
                              void* d_out, int out_size, void* d_ws, size_t ws_size,
                              hipStream_t stream) {
    const float* x    = (const float*)d_in[0];
    const int*   ei   = (const int*)d_in[1];
    const int*   batch= (const int*)d_in[2];
    const float* Wq   = (const float*)d_in[3];
    const float* bq   = (const float*)d_in[4];
    const float* Wk   = (const float*)d_in[5];
    const float* bk   = (const float*)d_in[6];
    const float* Wv   = (const float*)d_in[7];
    const float* bv   = (const float*)d_in[8];
    const float* Wsp  = (const float*)d_in[9];
    const float* bsp  = (const float*)d_in[10];
    const float* W1   = (const float*)d_in[11];
    const float* b1   = (const float*)d_in[12];
    const float* W2   = (const float*)d_in[13];
    const float* b2   = (const float*)d_in[14];
    float* out = (float*)d_out;
    float* pooled = out + NG * 10;

    const int* srcv = ei;
    const int* dstv = ei + NE;

    const size_t NEL = (size_t)NN * DD;
    ushort_t* hbf = (ushort_t*)d_ws;
    ushort_t* qb  = hbf + NEL;
    ushort_t* skb = qb  + NEL;
    unsigned char* kv8 = (unsigned char*)(skb + NEL);
    u32* binbuf   = (u32*)(kv8 + (size_t)NN * 128);
    int* gcur     = (int*)(binbuf + (size_t)NBUK * BCAP);
    int* gdh      = gcur + NBUK;
    int* gdcur    = gdh + NDC;
    int* rowstart = gdcur + NDC;
    int* csr_src  = rowstart + (NN + 1);
    int* perm     = csr_src + NE;
    ushort_t* wpack = (ushort_t*)(perm + NN);

    int totOut = NG * 10 + NL * NG * DD;
    int zeroBlocks = (totOut + 255) / 256;

    zero_k<<<2, 256, 0, stream>>>(gcur, gdh, gdcur);
    fused_k<<<NL * 4 + NBLK + zeroBlocks, 256, 0, stream>>>(
        Wq, Wk, Wv, Wsp, wpack, srcv, dstv, binbuf, gcur, out, totOut);
    csr_k<<<NBUK, 256, 0, stream>>>(binbuf, gcur, rowstart, csr_src, gdh);

    int gtiles = (NN + 63) / 64;
    int poolblocks = (NN + POOL_ROWS - 1) / POOL_ROWS;
    for (int l = 0; l < NL; l++) {
        int tailMode = (l == 0) ? 2 : 1;
        int extra = (l == 0) ? DPERM_BLOCKS : poolblocks;
        gemm4pool_k<<<gtiles + extra, 256, 0, stream>>>(
            hbf, (l == 0) ? x : nullptr, wpack + (size_t)l * 4 * 8 * 512,
            bq + l * DD, bk + l * DD, bv + l * DD, bsp + l * DD,
            qb, kv8, skb, batch,
            (l > 0) ? (pooled + (l - 1) * NG * DD) : nullptr, gtiles, tailMode,
            rowstart, gdh, gdcur, perm);
        agg_k<<<(NN + 31) / 32, 256, 0, stream>>>(qb, kv8, skb, rowstart, csr_src, perm, hbf);
    }
    pool_k<<<poolblocks, 256, 0, stream>>>(hbf, batch, pooled + 2 * NG * DD);
    head_k<<<NG, 64, 0, stream>>>(pooled + 2 * NG * DD, W1, b1, W2, b2, out);
}